// Round 7
// baseline (116.326 us; speedup 1.0000x reference)
//
#include <hip/hip_runtime.h>
#include <hip/hip_bf16.h>

// MoE conv via bf16 MFMA implicit GEMM — mega-block + full-DMA staging.
// x: [32,64,64,64] f32  idx: [32] i32  Wc: [4,128,64,3,3] f32  bc: [4,128] f32
// out: [32,128,64,64] f32
//
// R6 post-mortem: mega-block (1 block/CU) brought main ~42 -> ~34 us. Residual
// serial waste: x staging = 80 scalar f32 loads + 80 cvts + 20 ds_writes per
// thread, latency-exposed before the only barrier, reading x at f32 width.
//
// New: prep kernel (merged, one launch) additionally emits
//   xpre[b][h][ich8][w64][icl8] bf16  (16 MB in ws, LDS-transposed, coalesced)
// so each xs row-slice (r,ich) is ONE contiguous 1 KB run = one wave-level
// global_load_lds. Main's x staging: 10 DMA issues/wave + halo zeros. No cvt,
// no VGPR round-trip; x HBM traffic halves (bf16). Counted vmcnt(2) at tap 0
// drains x+w0 while tap-1 weights stay in flight (T4). Weight tap-dbuf DMA
// pipe, T1 XCD swizzle, T5 setprio all kept from R6.
// LDS main: 84480(xs) + 32768(wbuf) + 512(bias) = 117.8 KB, 1 block/CU.

#define IC 64
#define OC 128
#define HH 64
#define WW 64

// ws layout (ushort units): wre at 0 (294,912), xpre at 1 MB offset (8.4M..)
#define XPRE 524288   // ushort index = 1 MB byte offset

typedef short short8 __attribute__((ext_vector_type(8)));
typedef ushort ushort8 __attribute__((ext_vector_type(8)));
typedef float float16 __attribute__((ext_vector_type(16)));

typedef const __attribute__((address_space(1))) void gas_t;
typedef __attribute__((address_space(3))) void las_t;

static __device__ __forceinline__ ushort f2bf(float v) {
    __hip_bfloat16 h = __float2bfloat16(v);
    return *(ushort*)&h;
}

// ---------------- pre-kernel: x transpose + weight reorder (merged) --------
// bid < 2048: x-transpose. Block = (b,h): read 64ic x 64w f32 (coalesced
//   256B/instr), bf16 into LDS [ich][w][icl], write 8 KB contiguous ushort8.
// bid >= 2048: weight reorder (R2 version) -> [e][tap][ich8][oc128][icl8].
__global__ __launch_bounds__(256)
void prep(const float* __restrict__ x, const float* __restrict__ Wc,
          ushort* __restrict__ ws) {
    const int bid = blockIdx.x;
    const int t   = threadIdx.x;
    if (bid < 2048) {
        __shared__ ushort lx[4096];         // [ich][w][icl] 8 KB
        const int b = bid >> 6, h = bid & 63;
        const int w = t & 63;
        const float* xb = x + (size_t)b * 262144 + (size_t)h * 64 + w;
#pragma unroll
        for (int j = 0; j < 16; ++j) {
            const int ic = (t >> 6) * 16 + j;
            lx[((ic >> 3) * 64 + w) * 8 + (ic & 7)] = f2bf(xb[(size_t)ic * 4096]);
        }
        __syncthreads();
        ushort* ox = ws + XPRE + (size_t)bid * 4096;
#pragma unroll
        for (int k = 0; k < 2; ++k) {
            const int c = k * 256 + t;
            *(ushort8*)(ox + c * 8) = *(ushort8*)(lx + c * 8);
        }
    } else {
        __shared__ ushort lw[4 * 584];      // 4672 B
        const int bid2 = bid - 2048;        // 0..127
        const int e   = bid2 >> 5;
        const int oc0 = (bid2 & 31) * 4;
        const float* src = Wc + (size_t)(e * 128 + oc0) * 576;
#pragma unroll
        for (int k = 0; k < 9; ++k) {       // 9*256 = 2304 floats
            const int f   = k * 256 + t;
            const int ocl = f / 576;
            const int rem = f - ocl * 576;  // ic*9 + tap
            lw[ocl * 584 + rem] = f2bf(src[f]);
        }
        __syncthreads();
#pragma unroll
        for (int k = 0; k < 2; ++k) {
            const int n = k * 256 + t;      // 0..287 = tap(9) x ich(8) x ocl(4)
            if (n < 288) {
                const int ocl = n & 3, ich = (n >> 2) & 7, tap = n >> 5;
                ushort8 v;
#pragma unroll
                for (int icl = 0; icl < 8; ++icl)
                    v[icl] = lw[ocl * 584 + (ich * 8 + icl) * 9 + tap];
                *(ushort8*)(ws +
                    ((((size_t)(e * 9 + tap) * 8 + ich) * 128 + oc0 + ocl) * 8)) = v;
            }
        }
    }
}

// ---------------- main kernel ----------------
__global__ __launch_bounds__(512, 2)
void moe_conv_mfma(const ushort* __restrict__ ws, const int* __restrict__ idx,
                   const float* __restrict__ bc, float* __restrict__ out) {
    __shared__ __align__(16) ushort xs[10 * 8 * 66 * 8];  // [r][ich][hc][icl] 84480 B
    __shared__ __align__(16) ushort wbuf[2][8192];        // tap dbuf, 2x16 KB
    __shared__ float bias[128];

    const int t = threadIdx.x;

    // T1: XCD c (= lin%8) owns nw in [32c,32c+32) = samples 4c..4c+3, whole.
    const int lin = blockIdx.x;                 // 0..255
    const int nw  = (lin & 7) * 32 + (lin >> 3);
    const int b   = nw >> 3;                    // sample 0..31
    const int rq  = nw & 7;                     // row-block 0..7
    const int row0 = rq * 8;
    const int e    = ((unsigned)idx[b]) & 3;    // hardened expert index

    // --- per-lane MFMA coordinates ---
    const int lane31 = t & 31;
    const int lane64 = t & 63;
    const int lhi    = (t >> 5) & 1;
    const int wv     = t >> 6;            // 0..7 = output row within block

    const ushort* we = ws + (size_t)e * 9 * 8192;    // e-slice: 73,728 bf16

    // --- issue tap-0 weight DMA: 16 KB / 512 thr / 16B = 2 per thread ---
#pragma unroll
    for (int i = 0; i < 2; ++i) {
        __builtin_amdgcn_global_load_lds(
            (gas_t*)(we + i * 4096 + t * 8),
            (las_t*)&wbuf[0][i * 4096 + t * 8], 16, 0, 0);
    }

    // --- x staging via DMA: run (r,ich) = 1 KB contiguous in xpre -> one
    //     wave-level global_load_lds (64 lanes x 16B into xs cols 1..64) ---
    const ushort* xpre_b = ws + XPRE + (size_t)b * 262144;   // [h][ich][w][icl]
#pragma unroll
    for (int ich = 0; ich < 8; ++ich) {   // wave wv stages row r = wv
        const int gr = row0 - 1 + wv;
        ushort* dst = &xs[((wv * 8 + ich) * 66 + 1) * 8];
        if ((unsigned)gr < 64u) {
            __builtin_amdgcn_global_load_lds(
                (gas_t*)(xpre_b + ((size_t)gr * 8 + ich) * 512 + lane64 * 8),
                (las_t*)dst, 16, 0, 0);
        } else {
            ushort8 z = {0, 0, 0, 0, 0, 0, 0, 0};
            *(ushort8*)(dst + lane64 * 8) = z;
        }
    }
#pragma unroll
    for (int k = 0; k < 2; ++k) {         // extra rows 8,9: 16 runs / 8 waves
        const int ei = wv * 2 + k;        // 0..15
        const int r  = 8 + (ei >> 3), ich = ei & 7;
        const int gr = row0 - 1 + r;
        ushort* dst = &xs[((r * 8 + ich) * 66 + 1) * 8];
        if ((unsigned)gr < 64u) {
            __builtin_amdgcn_global_load_lds(
                (gas_t*)(xpre_b + ((size_t)gr * 8 + ich) * 512 + lane64 * 8),
                (las_t*)dst, 16, 0, 0);
        } else {
            ushort8 z = {0, 0, 0, 0, 0, 0, 0, 0};
            *(ushort8*)(dst + lane64 * 8) = z;
        }
    }

    // --- halo-column zeros (hc = 0, 65) + bias stage ---
    if (t < 320) {  // r(10) x ich(8) x side(2) x q(2)
        const int r = t >> 5, rem = t & 31;
        const int ich = rem >> 2, side = (rem >> 1) & 1, q = rem & 1;
        const int hc = side ? 65 : 0;
        ushort4 z = {0, 0, 0, 0};
        *(ushort4*)&xs[(((r * 8 + ich) * 66 + hc) * 8 + q * 4)] = z;
    } else if (t < 448) {
        bias[t - 320] = bc[e * OC + (t - 320)];
    }

    float16 acc[4][2];
#pragma unroll
    for (int g = 0; g < 4; ++g)
#pragma unroll
        for (int cg = 0; cg < 2; ++cg)
#pragma unroll
            for (int r = 0; r < 16; ++r) acc[g][cg][r] = 0.0f;

    // Lane-constant parts of addresses (ushort indices).
    const int xrow  = wv * 4224 + lane31 * 8;       // rr=wv+kh adds kh*4224
    const int abase = lane31 * 8;                   // + ich*1024 + g*256

    // --- 9-tap pipeline: issue tap+1 DMA, counted vmcnt, barrier, MFMA, barrier
#pragma unroll
    for (int tap = 0; tap < 9; ++tap) {
        const int cur = tap & 1;
        if (tap < 8) {
            const ushort* wt = we + (tap + 1) * 8192;
#pragma unroll
            for (int i = 0; i < 2; ++i) {
                __builtin_amdgcn_global_load_lds(
                    (gas_t*)(wt + i * 4096 + t * 8),
                    (las_t*)&wbuf[cur ^ 1][i * 4096 + t * 8], 16, 0, 0);
            }
            // 2 newer (tap+1's) stay in flight; at tap 0 this also drains
            // ALL x-staging + tap-0 weight DMAs. lgkmcnt(0): halo ds_writes.
            asm volatile("s_waitcnt vmcnt(2) lgkmcnt(0)" ::: "memory");
        } else {
            asm volatile("s_waitcnt vmcnt(0) lgkmcnt(0)" ::: "memory");
        }
        __builtin_amdgcn_s_barrier();   // tap data + xs visible to all waves

        const int kh = tap / 3;
        const int kw = tap - kh * 3;
        const int xtap = xrow + kh * 4224 + kw * 8;

        __builtin_amdgcn_s_setprio(1);
#pragma unroll
        for (int ks = 0; ks < 4; ++ks) {
            const int ich = ks * 2 + lhi;
            const int xo = xtap + ich * 528;
            const short8 b0 = *(const short8*)&xs[xo];
            const short8 b1 = *(const short8*)&xs[xo + 256];
            const int ao = abase + ich * 1024;
            const short8 a0 = *(const short8*)&wbuf[cur][ao];
            const short8 a1 = *(const short8*)&wbuf[cur][ao + 256];
            const short8 a2 = *(const short8*)&wbuf[cur][ao + 512];
            const short8 a3 = *(const short8*)&wbuf[cur][ao + 768];
            acc[0][0] = __builtin_amdgcn_mfma_f32_32x32x16_bf16(a0, b0, acc[0][0], 0, 0, 0);
            acc[0][1] = __builtin_amdgcn_mfma_f32_32x32x16_bf16(a0, b1, acc[0][1], 0, 0, 0);
            acc[1][0] = __builtin_amdgcn_mfma_f32_32x32x16_bf16(a1, b0, acc[1][0], 0, 0, 0);
            acc[1][1] = __builtin_amdgcn_mfma_f32_32x32x16_bf16(a1, b1, acc[1][1], 0, 0, 0);
            acc[2][0] = __builtin_amdgcn_mfma_f32_32x32x16_bf16(a2, b0, acc[2][0], 0, 0, 0);
            acc[2][1] = __builtin_amdgcn_mfma_f32_32x32x16_bf16(a2, b1, acc[2][1], 0, 0, 0);
            acc[3][0] = __builtin_amdgcn_mfma_f32_32x32x16_bf16(a3, b0, acc[3][0], 0, 0, 0);
            acc[3][1] = __builtin_amdgcn_mfma_f32_32x32x16_bf16(a3, b1, acc[3][1], 0, 0, 0);
        }
        __builtin_amdgcn_s_setprio(0);

        if (tap < 8)
            __builtin_amdgcn_s_barrier();   // wbuf[cur^1] reads done before
                                            // tap+2's DMA overwrites it
    }

    // --- epilogue: C/D layout col=lane&31, row=(reg&3)+8*(reg>>2)+4*(lane>>5) ---
#pragma unroll
    for (int g = 0; g < 4; ++g) {
        const int ocb = g * 32 + 4 * lhi;
#pragma unroll
        for (int reg = 0; reg < 16; ++reg) {
            const int oc = ocb + (reg & 3) + 8 * (reg >> 2);
            const float bv = bias[oc];
            const size_t base = (((size_t)b * OC + oc) * HH + (row0 + wv)) * WW;
            out[base + lane31]      = acc[g][0][reg] + bv;
            out[base + 32 + lane31] = acc[g][1][reg] + bv;
        }
    }
}

extern "C" void kernel_launch(void* const* d_in, const int* in_sizes, int n_in,
                              void* d_out, int out_size, void* d_ws, size_t ws_size,
                              hipStream_t stream) {
    const float* x   = (const float*)d_in[0];
    const int*   idx = (const int*)d_in[1];
    const float* Wc  = (const float*)d_in[2];
    const float* bc  = (const float*)d_in[3];
    float* out  = (float*)d_out;
    ushort* ws  = (ushort*)d_ws;   // wre 576 KB @0, xpre 16 MB @1 MB

    prep<<<2176, 256, 0, stream>>>(x, Wc, ws);      // 2048 x-blocks + 128 w-blocks
    moe_conv_mfma<<<256, 512, 0, stream>>>(ws, idx, bc, out);
}

// Round 9
// 112.002 us; speedup vs baseline: 1.0386x; 1.0386x over previous
//
#include <hip/hip_runtime.h>
#include <hip/hip_bf16.h>

// MoE conv via bf16 MFMA implicit GEMM — 2 blocks/CU, 16 waves/CU, DMA weights.
// x: [32,64,64,64] f32  idx: [32] i32  Wc: [4,128,64,3,3] f32  bc: [4,128] f32
// out: [32,128,64,64] f32
//
// R7 post-mortem: xpre round-trip (+32 MB HBM) was a net regression — reverted.
// Ledger: R1/R4 small-block mains 42 us; R6 mega-block (8 waves/CU, serial
// phases) ~34 us; R0 (2 blocks/CU, 16 waves/CU) ~28-30 us = best. Main is
// latency/phase-serialization bound (HBM floor 13, LDS 6-8, MFMA 2) -> TLP and
// cross-block staggering dominate per-wave efficiency.
//
// This round = R0's residency + proven pieces:
//  - grid 512 = exactly 2 blocks/CU (no generations), 512 thr = 8 thin waves
//    (2x2 accs of mfma_f32_32x32x16_bf16, 64 acc VGPRs).
//  - __launch_bounds__(512,4): VGPR <= 128 enforced -> 16 waves/CU guaranteed
//    (R0 never declared this — its occupancy was unverified).
//  - weights: SINGLE 16 KB LDS buffer via global_load_lds DMA, issued after
//    the close-barrier (no VGPR roundtrip / commit ds_writes of R0). Weight
//    slices are L2-hot (144 KB total) -> refill covered by co-resident block.
//  - x staged direct f32->bf16 (R6 path), 6 rows, 1.5x halo redundancy.
//  - prep = R2 LDS-transpose reorder (~4 us). T1 bijective XCD swizzle
//    (512 = 8x64). T5 setprio around MFMA cluster.
// LDS 50688(xs) + 16384(wbuf) + 512(bias) = 67.6 KB -> 2 blocks/CU.
//
// (Round-8 resubmission: R7's bench of this kernel failed with
// GPUAcquisitionTimeout — no data yet.)

#define IC 64
#define OC 128
#define HH 64
#define WW 64

typedef short short8 __attribute__((ext_vector_type(8)));
typedef ushort ushort8 __attribute__((ext_vector_type(8)));
typedef float float16 __attribute__((ext_vector_type(16)));

typedef const __attribute__((address_space(1))) void gas_t;
typedef __attribute__((address_space(3))) void las_t;

static __device__ __forceinline__ ushort f2bf(float v) {
    __hip_bfloat16 h = __float2bfloat16(v);
    return *(ushort*)&h;
}

// ---------------- pre-kernel: reorder + convert weights (R2 version) -------
// Block = (e, oc-group of 4). Phase 1: contiguous read of 2304 floats
// (coalesced), bf16 into LDS [ocl][ic*9+tap] with row pad 576->584. Phase 2:
// 288 ushort8 chunks, 8 LDS gathers each, coalesced 16B stores.
// Layout out: [e][tap][ich8][oc128][icl8].
__global__ __launch_bounds__(256)
void reorder_w(const float* __restrict__ Wc, ushort* __restrict__ wout) {
    __shared__ ushort lw[4 * 584];          // 4672 B
    const int t   = threadIdx.x;
    const int e   = blockIdx.x >> 5;        // 0..3
    const int oc0 = (blockIdx.x & 31) * 4;  // 0,4,..,124
    const float* src = Wc + (size_t)(e * 128 + oc0) * 576;
#pragma unroll
    for (int k = 0; k < 9; ++k) {           // 9*256 = 2304 floats
        const int f   = k * 256 + t;
        const int ocl = f / 576;
        const int rem = f - ocl * 576;      // ic*9 + tap
        lw[ocl * 584 + rem] = f2bf(src[f]);
    }
    __syncthreads();
#pragma unroll
    for (int k = 0; k < 2; ++k) {
        const int n = k * 256 + t;          // 0..287 = tap(9) x ich(8) x ocl(4)
        if (n < 288) {
            const int ocl = n & 3, ich = (n >> 2) & 7, tap = n >> 5;
            ushort8 v;
#pragma unroll
            for (int icl = 0; icl < 8; ++icl)
                v[icl] = lw[ocl * 584 + (ich * 8 + icl) * 9 + tap];
            *(ushort8*)(wout +
                ((((size_t)(e * 9 + tap) * 8 + ich) * 128 + oc0 + ocl) * 8)) = v;
        }
    }
}

// ---------------- main kernel ----------------
__global__ __launch_bounds__(512, 4)
void moe_conv_mfma(const float* __restrict__ x, const int* __restrict__ idx,
                   const ushort* __restrict__ wre, const float* __restrict__ bc,
                   float* __restrict__ out) {
    __shared__ __align__(16) ushort xs[6 * 8 * 66 * 8];  // [r][ich][hc][icl] 50688 B
    __shared__ __align__(16) ushort wbuf[8192];          // tap buffer, 16 KB
    __shared__ float bias[128];

    const int t = threadIdx.x;

    // T1: bijective XCD swizzle (512 = 8 x 64): XCD c owns work ids
    // [64c, 64c+64) = samples 4c..4c+3 whole (16 row-quads each).
    const int lin = blockIdx.x;                 // 0..511
    const int nw  = (lin & 7) * 64 + (lin >> 3);
    const int b   = nw >> 4;                    // sample 0..31
    const int rq  = nw & 15;                    // row quad 0..15
    const int row0 = rq * 4;
    const int e    = ((unsigned)idx[b]) & 3;    // hardened expert index

    // --- per-lane MFMA coordinates ---
    const int lane31 = t & 31;
    const int lhi    = (t >> 5) & 1;
    const int wv     = t >> 6;            // 0..7
    const int w0     = wv & 1;            // oc half
    const int pr     = wv >> 1;           // output row within quad, 0..3

    const ushort* we = wre + (size_t)e * 9 * 8192;   // e-slice: 73,728 bf16

    // --- issue tap-0 weight DMA: 16 KB / 512 thr / 16B = 2 per thread ---
    // dest = linear base + lane*16 within each wave's 1 KB stripe ✓
#pragma unroll
    for (int i = 0; i < 2; ++i) {
        __builtin_amdgcn_global_load_lds(
            (gas_t*)(we + i * 4096 + t * 8),
            (las_t*)&wbuf[i * 4096 + t * 8], 16, 0, 0);
    }

    // --- halo-column zeros (hc = 0, 65) + bias stage ---
    if (t < 192) {  // r(6) x ich(8) x side(2) x q(2)
        const int r = t >> 5, rem = t & 31;
        const int ich = rem >> 2, side = (rem >> 1) & 1, q = rem & 1;
        const int hc = side ? 65 : 0;
        ushort4 z = {0, 0, 0, 0};
        *(ushort4*)&xs[(((r * 8 + ich) * 66 + hc) * 8 + q * 4)] = z;
    } else if (t < 320) {
        bias[t - 192] = bc[e * OC + (t - 192)];
    }

    // --- x staging: fp32 [ic][h][w] -> bf16 [r(6)][ich][hc][icl] ---
    const float* xb = x + (size_t)b * IC * HH * WW;
    {
        const int gc   = t & 63;          // coalesced lane = w
        const int csel = t >> 6;          // 0..7
#pragma unroll
        for (int it = 0; it < 12; ++it) {
            const int combo = it * 8 + csel;       // 0..95 = r(6) x ich(8) x q(2)
            const int r = combo >> 4, rem = combo & 15;
            const int ich = rem >> 1, q = rem & 1;
            const int gr = row0 - 1 + r;
            ushort4 u = {0, 0, 0, 0};
            if ((unsigned)gr < (unsigned)HH) {
                const int ic0 = ich * 8 + q * 4;
                u.x = f2bf(xb[((ic0 + 0) * HH + gr) * WW + gc]);
                u.y = f2bf(xb[((ic0 + 1) * HH + gr) * WW + gc]);
                u.z = f2bf(xb[((ic0 + 2) * HH + gr) * WW + gc]);
                u.w = f2bf(xb[((ic0 + 3) * HH + gr) * WW + gc]);
            }
            *(ushort4*)&xs[(((r * 8 + ich) * 66 + (gc + 1)) * 8 + q * 4)] = u;
        }
    }

    float16 acc[2][2];
#pragma unroll
    for (int a = 0; a < 2; ++a)
#pragma unroll
        for (int cg = 0; cg < 2; ++cg)
#pragma unroll
            for (int r = 0; r < 16; ++r) acc[a][cg][r] = 0.0f;

    // --- 9-tap loop: wait own DMA, barrier, MFMA, barrier, issue next DMA ---
#pragma unroll
    for (int tap = 0; tap < 9; ++tap) {
        // own tap DMAs landed (+tap0: staging loads/ds_writes drained)
        asm volatile("s_waitcnt vmcnt(0) lgkmcnt(0)" ::: "memory");
        __builtin_amdgcn_s_barrier();   // all waves' DMAs landed; xs ready

        const int kh = tap / 3;
        const int kw = tap - kh * 3;
        const int rr = pr + kh;              // staged row 0..5
        const int hb = lane31 + kw;          // halo col for cg=0

        __builtin_amdgcn_s_setprio(1);
#pragma unroll
        for (int ks = 0; ks < 4; ++ks) {
            const int ich = ks * 2 + lhi;
            const short8 a0 = *(const short8*)&wbuf[(ich * 128 + w0 * 64 + lane31) * 8];
            const short8 a1 = *(const short8*)&wbuf[(ich * 128 + w0 * 64 + 32 + lane31) * 8];
            const short8 b0 = *(const short8*)&xs[((rr * 8 + ich) * 66 + hb) * 8];
            const short8 b1 = *(const short8*)&xs[((rr * 8 + ich) * 66 + hb + 32) * 8];
            acc[0][0] = __builtin_amdgcn_mfma_f32_32x32x16_bf16(a0, b0, acc[0][0], 0, 0, 0);
            acc[0][1] = __builtin_amdgcn_mfma_f32_32x32x16_bf16(a0, b1, acc[0][1], 0, 0, 0);
            acc[1][0] = __builtin_amdgcn_mfma_f32_32x32x16_bf16(a1, b0, acc[1][0], 0, 0, 0);
            acc[1][1] = __builtin_amdgcn_mfma_f32_32x32x16_bf16(a1, b1, acc[1][1], 0, 0, 0);
        }
        __builtin_amdgcn_s_setprio(0);

        __builtin_amdgcn_s_barrier();   // all waves done reading wbuf[tap]
        if (tap < 8) {                  // refill wbuf with tap+1 (L2-hot)
            const ushort* wt = we + (tap + 1) * 8192;
#pragma unroll
            for (int i = 0; i < 2; ++i) {
                __builtin_amdgcn_global_load_lds(
                    (gas_t*)(wt + i * 4096 + t * 8),
                    (las_t*)&wbuf[i * 4096 + t * 8], 16, 0, 0);
            }
        }
    }

    // --- epilogue: C/D layout col=lane&31, row=(reg&3)+8*(reg>>2)+4*(lane>>5) ---
#pragma unroll
    for (int a = 0; a < 2; ++a) {
        const int ocb = w0 * 64 + a * 32 + 4 * lhi;
#pragma unroll
        for (int reg = 0; reg < 16; ++reg) {
            const int oc = ocb + (reg & 3) + 8 * (reg >> 2);
            const float bv = bias[oc];
            const size_t base = (((size_t)b * OC + oc) * HH + (row0 + pr)) * WW;
            out[base + lane31]      = acc[a][0][reg] + bv;
            out[base + 32 + lane31] = acc[a][1][reg] + bv;
        }
    }
}

extern "C" void kernel_launch(void* const* d_in, const int* in_sizes, int n_in,
                              void* d_out, int out_size, void* d_ws, size_t ws_size,
                              hipStream_t stream) {
    const float* x   = (const float*)d_in[0];
    const int*   idx = (const int*)d_in[1];
    const float* Wc  = (const float*)d_in[2];
    const float* bc  = (const float*)d_in[3];
    float* out  = (float*)d_out;
    ushort* wre = (ushort*)d_ws;   // 294,912 bf16 = 576 KB scratch

    reorder_w<<<128, 256, 0, stream>>>(Wc, wre);    // 128*2304 = 294,912 = |Wc|
    moe_conv_mfma<<<512, 512, 0, stream>>>(x, idx, wre, bc, out);
}